// Round 3
// baseline (269.654 us; speedup 1.0000x reference)
//
#include <hip/hip_runtime.h>
#include <stdint.h>

// Problem constants (fixed by the reference): x is (128,1,512,512) fp32, k=2048.
#define B        128
#define ROW_N    262144                 // 512*512 elements per row
#define THREADS  256
#define BLOCKS_PER_ROW 16
#define BLK_CHUNK (ROW_N / BLOCKS_PER_ROW)   // 16384 floats per block
#define WAVE_CHUNK 4096                      // floats per wave (4 waves/block)

// Speculative exact pre-filter: keep ALL elements with |x| >= 2.5.
// k-th |x| ~= 2.66 for the N(0,1) input; >=2.5 population mean 3256, sigma 56.7
// per row -> n >= K at +21 sigma. n >= K guarantees the exact top-k lies in the
// candidate set. Any violation (segment cap, n < K, tie cap) -> exact fallback.
#define B0_BITS  0x40200000u  // bit pattern of 2.5f (abs-bits compare)
#define SEGS_PER_ROW 64       // 16 blocks x 4 waves, fixed segment per wave
#define SEGCAP   128          // entries per segment (mean 51, sigma 7.1, +10.7s)
#define FKSHIFT  17           // 14-bit fine key for tie resolution
#define FB0      8192         // (0x40000000 >> 17); keys here are >= 8196
#define NFB      8192         // fine buckets [8192, 16384)
#define TIE_CAP  2048         // ties in one fine bucket (mean ~190)
#define THREADS_SS 1024       // select block size (16 waves)
#define NWAVES_SS (THREADS_SS / 64)
// fallback histogram (coarse, full |x| range)
#define KSHIFT   19
#define NBUCKET  4096
#define FB_TIE_CAP 4096

// workspace layout (bytes); nothing needs pre-zeroing (counts are plain-stored
// by scan before select reads them; 0xAA poison elsewhere is never read).
#define OFF_WCNT 0                          // B * 64 u32 true per-wave counts
#define OFF_CAND 32768                      // B * 64 * SEGCAP * uint2 = 8 MiB

// ---- pass A: fused read-x / zero-out / compact |x| >= 2.5 -------------------
// One kernel moves both mandatory streams (134 MB read + 134 MB write) at the
// copy ceiling. Structure per group: 8 float4 loads issued FIRST (vmcnt retires
// in order, so the stores issued after never gate a load consumer), then 8
// plain float4 zero-stores (full 1KB/wave lines -> no write-allocate fetch;
// plain stores are the measured-6TB/s path on this box), then the ballot chain.
// Candidates go to FIXED per-wave global segments (no atomics, no pre-zeroing).
__global__ __launch_bounds__(THREADS) void scan_compact_zero_kernel(
        const float* __restrict__ x, float* __restrict__ out,
        unsigned* __restrict__ wcnt_arr, uint2* __restrict__ cand) {
    __shared__ uint2 wbuf[THREADS / 64][SEGCAP];   // 4 KiB, wave-private
    const int t = threadIdx.x;
    const int w = t >> 6;
    const int lane = t & 63;
    const unsigned long long lt = (1ull << lane) - 1ull;
    const int row = blockIdx.y;
    const int seg = blockIdx.x * (THREADS / 64) + w;            // 0..63
    const int wbase = blockIdx.x * BLK_CHUNK + w * WAVE_CHUNK;  // float offset
    const float4* src = (const float4*)(x + (size_t)row * ROW_N + wbase);
    float4* dst = (float4*)(out + (size_t)row * ROW_N + wbase);
    const float4 z = {0.f, 0.f, 0.f, 0.f};
    uint2* wb = wbuf[w];
    unsigned wcnt = 0;   // wave-uniform (derived from ballots only)

    for (int g = 0; g < 2; ++g) {
        float4 v[8];
#pragma unroll
        for (int u = 0; u < 8; ++u) v[u] = src[(g * 8 + u) * 64 + lane];
#pragma unroll
        for (int u = 0; u < 8; ++u) dst[(g * 8 + u) * 64 + lane] = z;
#pragma unroll
        for (int u = 0; u < 8; ++u) {
            const unsigned fbase = (unsigned)(wbase + ((g * 8 + u) * 64 + lane) * 4);
            const unsigned bb[4] = {__float_as_uint(v[u].x), __float_as_uint(v[u].y),
                                    __float_as_uint(v[u].z), __float_as_uint(v[u].w)};
#pragma unroll
            for (int c = 0; c < 4; ++c) {
                const bool pred = (bb[c] & 0x7FFFFFFFu) >= B0_BITS;   // ~1.24%
                const unsigned long long mask = __ballot(pred);
                if (pred) {
                    const unsigned p = wcnt + (unsigned)__popcll(mask & lt);
                    if (p < SEGCAP) wb[p] = make_uint2(fbase + (unsigned)c, bb[c]);
                }
                wcnt += (unsigned)__popcll(mask);
            }
        }
    }

    // flush to the fixed segment; plain stores only
    const unsigned total = wcnt < SEGCAP ? wcnt : SEGCAP;
    uint2* rseg = cand + ((size_t)row * SEGS_PER_ROW + seg) * SEGCAP;
    for (unsigned i = (unsigned)lane; i < total; i += 64) rseg[i] = wb[i];
    if (lane == 0) wcnt_arr[row * SEGS_PER_ROW + seg] = wcnt;   // true count
}

// -- pass B: select+scatter; exact fallback fused (block-uniform triggers) ----
__global__ __launch_bounds__(THREADS_SS) void select_scatter_kernel(
        const uint2* __restrict__ cand, const unsigned* __restrict__ wcnt_arr,
        const int* __restrict__ topk, const float* __restrict__ x,
        float* __restrict__ out) {
    const int row = blockIdx.x;
    const int t = threadIdx.x;
    const int lane = t & 63;
    const int w = t >> 6;
    const unsigned K = (unsigned)(*topk);
    float* rout = out + (size_t)row * ROW_N;

    // 48 KiB, aliased: fast path = h[NFB] + tidx/tbits[TIE_CAP];
    //                  fallback  = h[NBUCKET] + tidx/tbits[FB_TIE_CAP]. Both 12288 u32.
    __shared__ unsigned smem[NFB + 2 * TIE_CAP];
    __shared__ unsigned cnt_s[SEGS_PER_ROW];
    __shared__ unsigned wsum[NWAVES_SS];
    __shared__ unsigned tcnt;
    __shared__ unsigned sn, sof;
    __shared__ int sb, sneed;

    if (t < SEGS_PER_ROW) cnt_s[t] = wcnt_arr[row * SEGS_PER_ROW + t];
    __syncthreads();
    if (w == 0) {   // wave 0: n = sum counts, oflow = any count > SEGCAP
        unsigned c = cnt_s[lane];
        unsigned o = (c > (unsigned)SEGCAP) ? 1u : 0u;
        unsigned ns = c;
#pragma unroll
        for (int d = 1; d < 64; d <<= 1) {
            ns += (unsigned)__shfl_xor((int)ns, d);
            o |= (unsigned)__shfl_xor((int)o, d);
        }
        if (lane == 0) { sn = ns; sof = o; }
    }
    __syncthreads();
    const unsigned n = sn;
    const unsigned of = sof;

    if (!(n < K || of)) {   // block-uniform
        // ---------------- fast path ----------------
        unsigned* h = smem;
        unsigned* tidx = smem + NFB;
        unsigned* tbits = smem + NFB + TIE_CAP;
        for (int i = t; i < NFB; i += THREADS_SS) h[i] = 0;
        if (t == 0) tcnt = 0;
        __syncthreads();

        // hist over candidates: wave w owns 4 contiguous segments (cnt ~51 < 64)
        const uint2* rc = cand + (size_t)row * SEGS_PER_ROW * SEGCAP;
#pragma unroll
        for (int j = 0; j < 4; ++j) {
            const int s = w * 4 + j;
            const unsigned c = cnt_s[s];
            for (unsigned i = (unsigned)lane; i < c; i += 64) {
                const uint2 e = rc[(size_t)s * SEGCAP + i];
                atomicAdd(&h[((e.y & 0x7FFFFFFFu) >> FKSHIFT) - FB0], 1u);
            }
        }
        __syncthreads();

        // suffix counts: thread t owns PER buckets in descending order
        const int PER = NFB / THREADS_SS;   // 8
        unsigned s = 0;
#pragma unroll
        for (int i = 0; i < PER; ++i) s += h[NFB - 1 - (t * PER + i)];
        // block-wide exclusive scan over thread sums (wave shuffles + wave sums)
        unsigned v = s;
#pragma unroll
        for (int d = 1; d < 64; d <<= 1) {
            const unsigned o2 = __shfl_up(v, d);
            if (lane >= d) v += o2;
        }
        if (lane == 63) wsum[w] = v;
        __syncthreads();
        unsigned cum = v - s;               // exclusive within wave
#pragma unroll
        for (int i = 0; i < NWAVES_SS; ++i) cum += (i < w) ? wsum[i] : 0u;
#pragma unroll
        for (int i = 0; i < PER; ++i) {
            const int brel = NFB - 1 - (t * PER + i);
            const unsigned c = h[brel];
            if (cum < K && cum + c >= K) {   // unique crossing
                sb = brel + FB0;
                sneed = (int)(K - cum);
            }
            cum += c;
        }
        __syncthreads();
        const int b = sb;
        const int need = sneed;
        if (h[b - FB0] <= (unsigned)TIE_CAP) {   // block-uniform; before any writes
            // scatter winners above the tie bucket; collect ties
#pragma unroll
            for (int j = 0; j < 4; ++j) {
                const int sgi = w * 4 + j;
                const unsigned c = cnt_s[sgi];
                for (unsigned i = (unsigned)lane; i < c; i += 64) {
                    const uint2 e = rc[(size_t)sgi * SEGCAP + i];
                    const int fk = (int)((e.y & 0x7FFFFFFFu) >> FKSHIFT);
                    if (fk > b) {
                        rout[e.x] = __uint_as_float(e.y);
                    } else if (fk == b) {
                        const unsigned p = atomicAdd(&tcnt, 1u);
                        tidx[p] = e.x; tbits[p] = e.y;   // p < TIE_CAP by hist check
                    }
                }
            }
            __syncthreads();
            // exact rank among ties: desc |x| bits, asc index (matches lax.top_k)
            const int c = (int)tcnt;
            for (int i = t; i < c; i += THREADS_SS) {
                const unsigned bits = tbits[i], idx = tidx[i];
                const uint64_t key = ((uint64_t)(bits & 0x7FFFFFFFu) << 32) | (uint64_t)(~idx);
                int rank = 0;
                for (int j = 0; j < c; ++j) {
                    const uint64_t kj = ((uint64_t)(tbits[j] & 0x7FFFFFFFu) << 32) | (uint64_t)(~tidx[j]);
                    rank += (kj > key) ? 1 : 0;
                }
                if (rank < need) rout[idx] = __uint_as_float(bits);
            }
            return;
        }
        // tie-bucket overflow: fall through to exact fallback (nothing written yet)
    }

    // ---------------- exact fallback (normally never runs) ----------------
    __syncthreads();   // all threads done reading smem from the fast path
    {
        unsigned* h = smem;
        unsigned* tidx = smem + NBUCKET;
        unsigned* tbits = smem + NBUCKET + FB_TIE_CAP;
        for (int i = t; i < NBUCKET; i += THREADS_SS) h[i] = 0;
        if (t == 0) tcnt = 0;
        __syncthreads();

        const float4* xr = (const float4*)(x + (size_t)row * ROW_N);
        for (int i4 = t; i4 < ROW_N / 4; i4 += THREADS_SS) {
            const float4 v4 = xr[i4];
            atomicAdd(&h[(__float_as_uint(v4.x) & 0x7FFFFFFFu) >> KSHIFT], 1u);
            atomicAdd(&h[(__float_as_uint(v4.y) & 0x7FFFFFFFu) >> KSHIFT], 1u);
            atomicAdd(&h[(__float_as_uint(v4.z) & 0x7FFFFFFFu) >> KSHIFT], 1u);
            atomicAdd(&h[(__float_as_uint(v4.w) & 0x7FFFFFFFu) >> KSHIFT], 1u);
        }
        __syncthreads();

        const int PER = NBUCKET / THREADS_SS;   // 4
        unsigned s = 0;
#pragma unroll
        for (int i = 0; i < PER; ++i) s += h[NBUCKET - 1 - (t * PER + i)];
        unsigned v = s;
#pragma unroll
        for (int d = 1; d < 64; d <<= 1) {
            const unsigned o2 = __shfl_up(v, d);
            if (lane >= d) v += o2;
        }
        if (lane == 63) wsum[w] = v;
        __syncthreads();
        unsigned cum = v - s;
#pragma unroll
        for (int i = 0; i < NWAVES_SS; ++i) cum += (i < w) ? wsum[i] : 0u;
#pragma unroll
        for (int i = 0; i < PER; ++i) {
            const int bucket = NBUCKET - 1 - (t * PER + i);
            const unsigned c = h[bucket];
            if (cum < K && cum + c >= K) { sb = bucket; sneed = (int)(K - cum); }
            cum += c;
        }
        __syncthreads();
        const int b = sb;
        const int need = sneed;

        for (int i4 = t; i4 < ROW_N / 4; i4 += THREADS_SS) {
            const float4 v4 = xr[i4];
            const unsigned bits4[4] = {__float_as_uint(v4.x), __float_as_uint(v4.y),
                                       __float_as_uint(v4.z), __float_as_uint(v4.w)};
#pragma unroll
            for (int c = 0; c < 4; ++c) {
                const int key = (int)((bits4[c] & 0x7FFFFFFFu) >> KSHIFT);
                if (key > b) {
                    rout[i4 * 4 + c] = __uint_as_float(bits4[c]);
                } else if (key == b) {
                    const unsigned p = atomicAdd(&tcnt, 1u);
                    if (p < FB_TIE_CAP) { tidx[p] = (unsigned)(i4 * 4 + c); tbits[p] = bits4[c]; }
                }
            }
        }
        __syncthreads();
        const int c = (int)(tcnt < (unsigned)FB_TIE_CAP ? tcnt : (unsigned)FB_TIE_CAP);
        for (int i = t; i < c; i += THREADS_SS) {
            const unsigned bits = tbits[i], idx = tidx[i];
            const uint64_t key = ((uint64_t)(bits & 0x7FFFFFFFu) << 32) | (uint64_t)(~idx);
            int rank = 0;
            for (int j = 0; j < c; ++j) {
                const uint64_t kj = ((uint64_t)(tbits[j] & 0x7FFFFFFFu) << 32) | (uint64_t)(~tidx[j]);
                rank += (kj > key) ? 1 : 0;
            }
            if (rank < need) rout[idx] = __uint_as_float(bits);
        }
    }
}

extern "C" void kernel_launch(void* const* d_in, const int* in_sizes, int n_in,
                              void* d_out, int out_size, void* d_ws, size_t ws_size,
                              hipStream_t stream) {
    const float* x = (const float*)d_in[0];
    const int* topk = (const int*)d_in[1];
    float* out = (float*)d_out;
    char* ws = (char*)d_ws;

    unsigned* wcnt_arr = (unsigned*)(ws + OFF_WCNT);
    uint2* cand        = (uint2*)(ws + OFF_CAND);

    // fused: read x + zero-fill out + fixed-segment candidate compaction
    // (no atomics, no pre-zeroed state, one launch for both mandatory streams)
    dim3 gridA(BLOCKS_PER_ROW, B);  // 16 x 128 = 2048 blocks, 8/CU
    scan_compact_zero_kernel<<<gridA, THREADS, 0, stream>>>(x, out, wcnt_arr, cand);

    // fused select + scatter + inline exact fallback
    select_scatter_kernel<<<B, THREADS_SS, 0, stream>>>(cand, wcnt_arr, topk, x, out);
}

// Round 4
// 253.021 us; speedup vs baseline: 1.0657x; 1.0657x over previous
//
#include <hip/hip_runtime.h>
#include <stdint.h>

// Problem constants (fixed by the reference): x is (128,1,512,512) fp32, k=2048.
#define B        128
#define ROW_N    262144                 // 512*512 elements per row
#define THREADS  256
#define BLOCKS_PER_ROW 16
#define BLK_CHUNK (ROW_N / BLOCKS_PER_ROW)   // 16384 floats per block
#define WAVE_CHUNK 4096                      // floats per wave (4 waves/block)

// Speculative exact pre-filter: keep ALL elements with |x| >= 2.5.
// k-th |x| ~= 2.66 for the N(0,1) input; >=2.5 population mean 3256, sigma 56.7
// per row -> n >= K at +21 sigma. n >= K guarantees the exact top-k lies in the
// candidate set. Any violation (segment cap, n < K, n > LDS cap, tie cap)
// -> exact in-block fallback.
#define B0_BITS  0x40200000u  // bit pattern of 2.5f (abs-bits compare)
#define SEGS_PER_ROW 64       // 16 blocks x 4 waves, fixed segment per wave
#define SEGCAP   128          // entries per segment (mean 51, sigma 7.1, +10.7s)
#define FKSHIFT  17           // fine key for tie resolution
#define FB0      8192         // (0x40000000 >> 17); keys here are >= 8196
#define NFB      1024         // fine buckets [8192, 9216) + exact clamp bucket:
                              // covers |x| < 65536; higher keys clamp to bucket
                              // 1023, which tie-rank resolves EXACTLY (full-bit
                              // compare), so correctness holds for any input.
#define CAND_LDS 4096         // per-row LDS candidate cap (+14.8 sigma)
#define TIE_CAP  2048         // ties in one fine bucket (mean ~190)
#define THREADS_SS 1024       // select block size (16 waves)
#define NWAVES_SS (THREADS_SS / 64)
// fallback histogram (coarse, full |x| range)
#define KSHIFT   19
#define NBUCKET  4096
#define FB_TIE_CAP 4096

// shared scratch (u32 words), aliased:
//   fast:     cbuf[4096 uint2] (8192) | h[1024] | tidx[2048] | tbits[2048] = 13312
//   fallback: h[4096] | tidx[4096] | tbits[4096]                          = 12288
#define SMEM_WORDS 13312

// workspace layout (bytes); nothing needs pre-zeroing (counts are plain-stored
// by scan before select reads them; 0xAA poison elsewhere is never read).
#define OFF_WCNT 0                          // B * 64 u32 true per-wave counts
#define OFF_CAND 32768                      // B * 64 * SEGCAP * uint2 = 8 MiB

// ---- pass A: pure-read scan + wave compaction of |x| >= 2.5 -----------------
// 8 float4 loads in flight per wave; candidates go to a FIXED per-wave global
// segment (no atomics, no dependence on zeroed memory). True count is plain-
// stored; count > SEGCAP signals dropped entries -> select runs exact fallback.
__global__ __launch_bounds__(THREADS) void scan_compact_kernel(
        const float* __restrict__ x, unsigned* __restrict__ wcnt_arr,
        uint2* __restrict__ cand) {
    __shared__ uint2 wbuf[THREADS / 64][SEGCAP];   // 4 KiB, wave-private
    const int t = threadIdx.x;
    const int w = t >> 6;
    const int lane = t & 63;
    const unsigned long long lt = (1ull << lane) - 1ull;
    const int row = blockIdx.y;
    const int seg = blockIdx.x * (THREADS / 64) + w;            // 0..63
    const int wbase = blockIdx.x * BLK_CHUNK + w * WAVE_CHUNK;  // float offset
    const float4* src = (const float4*)(x + (size_t)row * ROW_N + wbase);
    uint2* wb = wbuf[w];
    unsigned wcnt = 0;   // wave-uniform (derived from ballots only)

    for (int g = 0; g < 2; ++g) {
        float4 v[8];
#pragma unroll
        for (int u = 0; u < 8; ++u) v[u] = src[(g * 8 + u) * 64 + lane];
#pragma unroll
        for (int u = 0; u < 8; ++u) {
            const unsigned fbase = (unsigned)(wbase + ((g * 8 + u) * 64 + lane) * 4);
            const unsigned bb[4] = {__float_as_uint(v[u].x), __float_as_uint(v[u].y),
                                    __float_as_uint(v[u].z), __float_as_uint(v[u].w)};
#pragma unroll
            for (int c = 0; c < 4; ++c) {
                const bool pred = (bb[c] & 0x7FFFFFFFu) >= B0_BITS;   // ~1.24%
                const unsigned long long mask = __ballot(pred);
                if (pred) {
                    const unsigned p = wcnt + (unsigned)__popcll(mask & lt);
                    if (p < SEGCAP) wb[p] = make_uint2(fbase + (unsigned)c, bb[c]);
                }
                wcnt += (unsigned)__popcll(mask);
            }
        }
    }

    // flush to the fixed segment; plain stores only
    const unsigned total = wcnt < SEGCAP ? wcnt : SEGCAP;
    uint2* rseg = cand + ((size_t)row * SEGS_PER_ROW + seg) * SEGCAP;
    for (unsigned i = (unsigned)lane; i < total; i += 64) rseg[i] = wb[i];
    if (lane == 0) wcnt_arr[row * SEGS_PER_ROW + seg] = wcnt;   // true count
}

// -- pass B: select+scatter; candidates staged in LDS ONCE (single global
//    pass); exact fallback fused (all triggers block-uniform) -----------------
__global__ __launch_bounds__(THREADS_SS) void select_scatter_kernel(
        const uint2* __restrict__ cand, const unsigned* __restrict__ wcnt_arr,
        const int* __restrict__ topk, const float* __restrict__ x,
        float* __restrict__ out) {
    const int row = blockIdx.x;
    const int t = threadIdx.x;
    const int lane = t & 63;
    const int w = t >> 6;
    const unsigned K = (unsigned)(*topk);
    float* rout = out + (size_t)row * ROW_N;

    __shared__ unsigned smem[SMEM_WORDS];      // 52 KiB, aliased (see top)
    __shared__ unsigned cnt_s[SEGS_PER_ROW];
    __shared__ unsigned seg_off[SEGS_PER_ROW];
    __shared__ unsigned wsum[NWAVES_SS];
    __shared__ unsigned tcnt;
    __shared__ unsigned sn, sof;
    __shared__ int sb, sneed;

    if (t < SEGS_PER_ROW) cnt_s[t] = wcnt_arr[row * SEGS_PER_ROW + t];
    __syncthreads();
    if (w == 0) {   // wave 0: n, overflow flag, and exclusive segment offsets
        const unsigned c = cnt_s[lane];
        unsigned o = (c > (unsigned)SEGCAP) ? 1u : 0u;
        unsigned v = c;
#pragma unroll
        for (int d = 1; d < 64; d <<= 1) {
            const unsigned o2 = __shfl_up(v, d);
            if (lane >= d) v += o2;
        }
        seg_off[lane] = v - c;                  // exclusive prefix (valid iff !of)
        const unsigned tot = (unsigned)__shfl((int)v, 63);
#pragma unroll
        for (int d = 1; d < 64; d <<= 1) o |= (unsigned)__shfl_xor((int)o, d);
        if (lane == 0) { sn = tot; sof = o; }
    }
    __syncthreads();
    const unsigned n = sn;
    const unsigned of = sof;

    if (!(n < K || n > (unsigned)CAND_LDS || of)) {   // block-uniform
        // ---------------- fast path ----------------
        uint2* cb = (uint2*)smem;                     // [0, 8192) words
        unsigned* h = smem + 2 * CAND_LDS;            // [8192, 9216)
        unsigned* tidx = h + NFB;                     // [9216, 11264)
        unsigned* tbits = tidx + TIE_CAP;             // [11264, 13312)
        h[t] = 0;                                     // NFB == THREADS_SS
        if (t == 0) tcnt = 0;

        // stage candidates into LDS, compacted (wave w owns 4 segments)
        const uint2* rc = cand + (size_t)row * SEGS_PER_ROW * SEGCAP;
#pragma unroll
        for (int j = 0; j < 4; ++j) {
            const int s = w * 4 + j;
            const unsigned c = cnt_s[s];
            const unsigned off = seg_off[s];
            for (unsigned i = (unsigned)lane; i < c; i += 64)
                cb[off + i] = rc[(size_t)s * SEGCAP + i];
        }
        __syncthreads();

        // hist from LDS (clamped fine key; clamp bucket resolved exactly below)
        for (unsigned i = (unsigned)t; i < n; i += THREADS_SS) {
            unsigned kr = ((cb[i].y & 0x7FFFFFFFu) >> FKSHIFT) - FB0;
            kr = kr < (unsigned)NFB ? kr : (unsigned)(NFB - 1);
            atomicAdd(&h[kr], 1u);
        }
        __syncthreads();

        // suffix scan, one bucket per thread (descending)
        const int brel = NFB - 1 - t;
        const unsigned bc = h[brel];
        unsigned v = bc;
#pragma unroll
        for (int d = 1; d < 64; d <<= 1) {
            const unsigned o2 = __shfl_up(v, d);
            if (lane >= d) v += o2;
        }
        if (lane == 63) wsum[w] = v;
        __syncthreads();
        unsigned cum = v - bc;                 // exclusive within wave
#pragma unroll
        for (int i = 0; i < NWAVES_SS; ++i) cum += (i < w) ? wsum[i] : 0u;
        if (cum < K && cum + bc >= K) {        // unique crossing
            sb = brel;
            sneed = (int)(K - cum);
        }
        __syncthreads();
        const int b = sb;                      // relative bucket
        const int need = sneed;
        if (h[b] <= (unsigned)TIE_CAP) {       // block-uniform; before any writes
            // scatter winners above the tie bucket; collect ties — from LDS
            for (unsigned i = (unsigned)t; i < n; i += THREADS_SS) {
                const uint2 e = cb[i];
                unsigned kr = ((e.y & 0x7FFFFFFFu) >> FKSHIFT) - FB0;
                kr = kr < (unsigned)NFB ? kr : (unsigned)(NFB - 1);
                if ((int)kr > b) {
                    rout[e.x] = __uint_as_float(e.y);
                } else if ((int)kr == b) {
                    const unsigned p = atomicAdd(&tcnt, 1u);
                    tidx[p] = e.x; tbits[p] = e.y;   // p < TIE_CAP by hist check
                }
            }
            __syncthreads();
            // exact rank among ties: desc |x| bits, asc index (matches lax.top_k)
            const int c = (int)tcnt;
            for (int i = t; i < c; i += THREADS_SS) {
                const unsigned bits = tbits[i], idx = tidx[i];
                const uint64_t key = ((uint64_t)(bits & 0x7FFFFFFFu) << 32) | (uint64_t)(~idx);
                int rank = 0;
                for (int j = 0; j < c; ++j) {
                    const uint64_t kj = ((uint64_t)(tbits[j] & 0x7FFFFFFFu) << 32) | (uint64_t)(~tidx[j]);
                    rank += (kj > key) ? 1 : 0;
                }
                if (rank < need) rout[idx] = __uint_as_float(bits);
            }
            return;
        }
        // tie-bucket overflow: fall through to exact fallback (nothing written yet)
    }

    // ---------------- exact fallback (normally never runs) ----------------
    __syncthreads();   // all threads done with smem from the fast path
    {
        unsigned* h = smem;                    // [0, 4096)
        unsigned* tidx = smem + NBUCKET;       // [4096, 8192)
        unsigned* tbits = smem + 2 * NBUCKET;  // [8192, 12288)
        for (int i = t; i < NBUCKET; i += THREADS_SS) h[i] = 0;
        if (t == 0) tcnt = 0;
        __syncthreads();

        const float4* xr = (const float4*)(x + (size_t)row * ROW_N);
        for (int i4 = t; i4 < ROW_N / 4; i4 += THREADS_SS) {
            const float4 v4 = xr[i4];
            atomicAdd(&h[(__float_as_uint(v4.x) & 0x7FFFFFFFu) >> KSHIFT], 1u);
            atomicAdd(&h[(__float_as_uint(v4.y) & 0x7FFFFFFFu) >> KSHIFT], 1u);
            atomicAdd(&h[(__float_as_uint(v4.z) & 0x7FFFFFFFu) >> KSHIFT], 1u);
            atomicAdd(&h[(__float_as_uint(v4.w) & 0x7FFFFFFFu) >> KSHIFT], 1u);
        }
        __syncthreads();

        const int PER = NBUCKET / THREADS_SS;   // 4
        unsigned s = 0;
#pragma unroll
        for (int i = 0; i < PER; ++i) s += h[NBUCKET - 1 - (t * PER + i)];
        unsigned v = s;
#pragma unroll
        for (int d = 1; d < 64; d <<= 1) {
            const unsigned o2 = __shfl_up(v, d);
            if (lane >= d) v += o2;
        }
        if (lane == 63) wsum[w] = v;
        __syncthreads();
        unsigned cum = v - s;
#pragma unroll
        for (int i = 0; i < NWAVES_SS; ++i) cum += (i < w) ? wsum[i] : 0u;
#pragma unroll
        for (int i = 0; i < PER; ++i) {
            const int bucket = NBUCKET - 1 - (t * PER + i);
            const unsigned c = h[bucket];
            if (cum < K && cum + c >= K) { sb = bucket; sneed = (int)(K - cum); }
            cum += c;
        }
        __syncthreads();
        const int b = sb;
        const int need = sneed;

        for (int i4 = t; i4 < ROW_N / 4; i4 += THREADS_SS) {
            const float4 v4 = xr[i4];
            const unsigned bits4[4] = {__float_as_uint(v4.x), __float_as_uint(v4.y),
                                       __float_as_uint(v4.z), __float_as_uint(v4.w)};
#pragma unroll
            for (int c = 0; c < 4; ++c) {
                const int key = (int)((bits4[c] & 0x7FFFFFFFu) >> KSHIFT);
                if (key > b) {
                    rout[i4 * 4 + c] = __uint_as_float(bits4[c]);
                } else if (key == b) {
                    const unsigned p = atomicAdd(&tcnt, 1u);
                    if (p < FB_TIE_CAP) { tidx[p] = (unsigned)(i4 * 4 + c); tbits[p] = bits4[c]; }
                }
            }
        }
        __syncthreads();
        const int c = (int)(tcnt < (unsigned)FB_TIE_CAP ? tcnt : (unsigned)FB_TIE_CAP);
        for (int i = t; i < c; i += THREADS_SS) {
            const unsigned bits = tbits[i], idx = tidx[i];
            const uint64_t key = ((uint64_t)(bits & 0x7FFFFFFFu) << 32) | (uint64_t)(~idx);
            int rank = 0;
            for (int j = 0; j < c; ++j) {
                const uint64_t kj = ((uint64_t)(tbits[j] & 0x7FFFFFFFu) << 32) | (uint64_t)(~tidx[j]);
                rank += (kj > key) ? 1 : 0;
            }
            if (rank < need) rout[idx] = __uint_as_float(bits);
        }
    }
}

extern "C" void kernel_launch(void* const* d_in, const int* in_sizes, int n_in,
                              void* d_out, int out_size, void* d_ws, size_t ws_size,
                              hipStream_t stream) {
    const float* x = (const float*)d_in[0];
    const int* topk = (const int*)d_in[1];
    float* out = (float*)d_out;
    char* ws = (char*)d_ws;

    unsigned* wcnt_arr = (unsigned*)(ws + OFF_WCNT);
    uint2* cand        = (uint2*)(ws + OFF_CAND);

    // zero-fill out via the rocclr fill path (measured ~6.05 TB/s on this box)
    hipMemsetAsync(out, 0, (size_t)B * ROW_N * sizeof(float), stream);

    // pure-read scan + fixed-segment candidate compaction (no atomics,
    // no pre-zeroed state required)
    dim3 gridA(BLOCKS_PER_ROW, B);  // 16 x 128 = 2048 blocks, 8/CU
    scan_compact_kernel<<<gridA, THREADS, 0, stream>>>(x, wcnt_arr, cand);

    // fused select + scatter (LDS-staged, single global pass) + exact fallback
    select_scatter_kernel<<<B, THREADS_SS, 0, stream>>>(cand, wcnt_arr, topk, x, out);
}